// Round 4
// baseline (16.053 us; speedup 1.0000x reference)
//
#include <hip/hip_runtime.h>

// Problem geometry (from reference): x is (B, H, T) = (4096, 1024, 26) f32.
// Only x[b, j, 6:12] for j in [0,26) is used:
//   q[b, j, k] = x[b, j, 6+k],  k in [0,6)
// cost(b,j) = 1/denom via Sherman-Morrison on M = 2I + 0.5 c c^T:
//   denom = 0.5*sum(L^2 s^2) - 0.125*(sum(L s c))^2 / (1 + 0.25*sum(c^2))
// Output = scalar sum over all (b, j).
//
// R3 post-mortem: two-dispatch structure = 11.7us; compute is a minor term.
// R4: single dispatch, last-block-done final reduction.
//  - completion counter in __device__ global (zero at load, reset by last
//    block each call -> stateless invariant, unaffected by d_ws poisoning)
//  - partials written/read with device-scope atomics (coherent point) to be
//    safe under per-XCD L2 non-coherence
//  - final reduce in fixed order -> bitwise deterministic

#define T_DIM 26
#define H_DIM 1024
#define TASKS_PER_B 26
#define BLK 256

__device__ unsigned g_done_ctr = 0;   // .bss: zero at module load

__global__ void cost_onepass_kernel(const float* __restrict__ x,
                                    unsigned long long* __restrict__ partial,
                                    float* __restrict__ out,
                                    int ntasks) {
    __shared__ double red[BLK / 64];
    __shared__ int is_last_s;

    const int t = blockIdx.x * BLK + threadIdx.x;
    double acc = 0.0;
    if (t < ntasks) {
        const int b = t / TASKS_PER_B;
        const int j = t - b * TASKS_PER_B;
        const float* q = x + (size_t)b * (H_DIM * T_DIM) + (size_t)j * T_DIM + 6;
        // q is 8-byte aligned (byte offset 104*j + 24): three float2 loads.
        const float2 q01 = *(const float2*)(q + 0);
        const float2 q23 = *(const float2*)(q + 2);
        const float2 q45 = *(const float2*)(q + 4);
        const float qa[6] = {q01.x, q01.y, q23.x, q23.y, q45.x, q45.y};

        float cq = 0.0f, sL2s2 = 0.0f, sLsc = 0.0f, sc2 = 0.0f;
#pragma unroll
        for (int i = 0; i < 6; ++i) {
            const float Li = (float)(i + 1) * 0.1f + 0.3f;  // matches reference f32 L
            cq += qa[i];
            float s, c;
            __sincosf(cq, &s, &c);
            sL2s2 += (Li * s) * (Li * s);
            sLsc  += Li * s * c;
            sc2   += c * c;
        }
        // Final combine + reciprocal in f64: protects against cancellation
        // when denom is small (cost spikes), costs ~nothing per thread.
        const double denom = 0.5 * (double)sL2s2
                           - 0.125 * (double)sLsc * (double)sLsc
                                   / (1.0 + 0.25 * (double)sc2);
        acc = 1.0 / denom;
    }

    // wave-64 butterfly reduce
#pragma unroll
    for (int off = 32; off >= 1; off >>= 1)
        acc += __shfl_down(acc, off, 64);

    const int lane = threadIdx.x & 63;
    const int wid  = threadIdx.x >> 6;
    if (lane == 0) red[wid] = acc;
    __syncthreads();

    if (threadIdx.x == 0) {
        double s = 0.0;
#pragma unroll
        for (int w = 0; w < BLK / 64; ++w) s += red[w];
        // Device-scope atomic write -> lands at the coherent point (safe
        // across non-coherent per-XCD L2s).
        atomicExch(&partial[blockIdx.x], (unsigned long long)__double_as_longlong(s));
        __threadfence();                       // release
        unsigned old = atomicAdd(&g_done_ctr, 1u);
        is_last_s = (old == gridDim.x - 1) ? 1 : 0;
    }
    __syncthreads();

    if (is_last_s) {
        __threadfence();                       // acquire
        const int nblocks = gridDim.x;
        double a = 0.0;
        // Device-scope atomic read (add 0) -> reads the coherent point.
        for (int i = threadIdx.x; i < nblocks; i += BLK)
            a += __longlong_as_double((long long)atomicAdd(&partial[i], 0ULL));
#pragma unroll
        for (int off = 32; off >= 1; off >>= 1)
            a += __shfl_down(a, off, 64);
        if (lane == 0) red[wid] = a;
        __syncthreads();
        if (threadIdx.x == 0) {
            double s = 0.0;
#pragma unroll
            for (int w = 0; w < BLK / 64; ++w) s += red[w];
            out[0] = (float)s;
            atomicExch(&g_done_ctr, 0u);       // restore invariant for next call
        }
    }
}

extern "C" void kernel_launch(void* const* d_in, const int* in_sizes, int n_in,
                              void* d_out, int out_size, void* d_ws, size_t ws_size,
                              hipStream_t stream) {
    const float* x = (const float*)d_in[0];
    // d_in[1] = cond (unused), d_in[2] = time (gives B)
    const int B = in_sizes[2];
    const int ntasks = B * TASKS_PER_B;
    const int nblocks = (ntasks + BLK - 1) / BLK;   // 416 for B=4096 (exact)

    unsigned long long* partial = (unsigned long long*)d_ws;
    float* out = (float*)d_out;

    cost_onepass_kernel<<<nblocks, BLK, 0, stream>>>(x, partial, out, ntasks);
}

// Round 5
// 12.107 us; speedup vs baseline: 1.3259x; 1.3259x over previous
//
#include <hip/hip_runtime.h>

// Problem geometry (from reference): x is (B, H, T) = (4096, 1024, 26) f32.
// Only x[b, j, 6:12] for j in [0,26) is used:
//   q[b, j, k] = x[b, j, 6+k],  k in [0,6)
// cost(b,j) = 1/denom via Sherman-Morrison on M = 2I + 0.5 c c^T:
//   denom = 0.5*sum(L^2 s^2) - 0.125*(sum(L s c))^2 / (1 + 0.25*sum(c^2))
// Output = scalar sum over all (b, j).  All costs > 0 (M is PD).
//
// R4 post-mortem: last-block-done with O(nblocks) atomic tail = +4.4us. This
// round: single dispatch, O(1) tail — one packed u64 atomicAdd per block:
//   bits [0,54):  block partial in fixed-point (scale 2^26, all positive)
//   bits [54,63): completion counter (+1<<54 per block)
// Integer adds are order-independent -> bitwise-deterministic sum. The block
// seeing counter==nblocks-1 in the returned 'old' already holds the full sum
// (old + its own add) -> no fence, no re-read loop. It writes out[0] and
// resets the global to 0 (invariant restored for next graph replay).

#define T_DIM 26
#define H_DIM 1024
#define TASKS_PER_B 26
#define BLK 256

#define CTR_SHIFT 54
#define FX_MASK ((1ULL << CTR_SHIFT) - 1ULL)
#define FX_SCALE 67108864.0   // 2^26

__device__ unsigned long long g_acc = 0ULL;   // .bss: zero at module load

__global__ void cost_onepass_kernel(const float* __restrict__ x,
                                    float* __restrict__ out,
                                    int ntasks) {
    __shared__ double red[BLK / 64];

    const int t = blockIdx.x * BLK + threadIdx.x;
    double acc = 0.0;
    if (t < ntasks) {
        const int b = t / TASKS_PER_B;
        const int j = t - b * TASKS_PER_B;
        const float* q = x + (size_t)b * (H_DIM * T_DIM) + (size_t)j * T_DIM + 6;
        // q is 8-byte aligned (byte offset 104*j + 24): three float2 loads.
        const float2 q01 = *(const float2*)(q + 0);
        const float2 q23 = *(const float2*)(q + 2);
        const float2 q45 = *(const float2*)(q + 4);
        const float qa[6] = {q01.x, q01.y, q23.x, q23.y, q45.x, q45.y};

        float cq = 0.0f, sL2s2 = 0.0f, sLsc = 0.0f, sc2 = 0.0f;
#pragma unroll
        for (int i = 0; i < 6; ++i) {
            const float Li = (float)(i + 1) * 0.1f + 0.3f;  // matches reference f32 L
            cq += qa[i];
            float s, c;
            __sincosf(cq, &s, &c);
            sL2s2 += (Li * s) * (Li * s);
            sLsc  += Li * s * c;
            sc2   += c * c;
        }
        // Final combine + reciprocal in f64 (cancellation safety, ~free).
        const double denom = 0.5 * (double)sL2s2
                           - 0.125 * (double)sLsc * (double)sLsc
                                   / (1.0 + 0.25 * (double)sc2);
        acc = 1.0 / denom;   // > 0 always
    }

    // wave-64 butterfly reduce
#pragma unroll
    for (int off = 32; off >= 1; off >>= 1)
        acc += __shfl_down(acc, off, 64);

    const int lane = threadIdx.x & 63;
    const int wid  = threadIdx.x >> 6;
    if (lane == 0) red[wid] = acc;
    __syncthreads();

    if (threadIdx.x == 0) {
        double s = 0.0;
#pragma unroll
        for (int w = 0; w < BLK / 64; ++w) s += red[w];

        // Pack: fixed-point partial (positive) + completion tick.
        const unsigned long long fx =
            (unsigned long long)__double2ll_rn(s * FX_SCALE);
        const unsigned long long add = (1ULL << CTR_SHIFT) + fx;
        const unsigned long long old = atomicAdd(&g_acc, add);

        if ((old >> CTR_SHIFT) == (unsigned long long)(gridDim.x - 1)) {
            // Every block's contribution is in (old + add). O(1) tail.
            const unsigned long long total_fx = (old + add) & FX_MASK;
            out[0] = (float)((double)total_fx / FX_SCALE);
            atomicExch(&g_acc, 0ULL);   // restore invariant for next replay
        }
    }
}

extern "C" void kernel_launch(void* const* d_in, const int* in_sizes, int n_in,
                              void* d_out, int out_size, void* d_ws, size_t ws_size,
                              hipStream_t stream) {
    const float* x = (const float*)d_in[0];
    // d_in[1] = cond (unused), d_in[2] = time (gives B)
    const int B = in_sizes[2];
    const int ntasks = B * TASKS_PER_B;
    const int nblocks = (ntasks + BLK - 1) / BLK;   // 416 for B=4096 (exact)

    float* out = (float*)d_out;
    cost_onepass_kernel<<<nblocks, BLK, 0, stream>>>(x, out, ntasks);
}

// Round 6
// 11.622 us; speedup vs baseline: 1.3812x; 1.0417x over previous
//
#include <hip/hip_runtime.h>

// Problem geometry (from reference): x is (B, H, T) = (4096, 1024, 26) f32.
// Only x[b, j, 6:12] for j in [0,26) is used:
//   q[b, j, k] = x[b, j, 6+k],  k in [0,6)
// cost(b,j) = 1/denom via Sherman-Morrison on M = 2I + 0.5 c c^T:
//   denom = 0.5*sum(L^2 s^2) - 0.125*(sum(L s c))^2 / (1 + 0.25*sum(c^2))
// Output = scalar sum over all (b, j).
//
// Final structure (best measured, R3 = 11.67us): two plain dispatches.
// Session findings: cooperative launch +40us (R2); last-block-done O(n)
// atomic tail +4.4us (R4); O(1) packed-atomic tail ~= two dispatches (R5).
// Under graph replay a second tiny dispatch is ~free; total time is a fixed
// harness/replay floor + ~2-3us latency-bound kernel (2.6 MB useful bytes).

#define T_DIM 26
#define H_DIM 1024
#define TASKS_PER_B 26
#define BLK 256

__global__ void cost_partial_kernel(const float* __restrict__ x,
                                    double* __restrict__ partial,
                                    int ntasks) {
    __shared__ double red[BLK / 64];

    const int t = blockIdx.x * BLK + threadIdx.x;
    double acc = 0.0;
    if (t < ntasks) {
        const int b = t / TASKS_PER_B;
        const int j = t - b * TASKS_PER_B;
        const float* q = x + (size_t)b * (H_DIM * T_DIM) + (size_t)j * T_DIM + 6;
        // q is 8-byte aligned (byte offset 104*j + 24): three float2 loads.
        const float2 q01 = *(const float2*)(q + 0);
        const float2 q23 = *(const float2*)(q + 2);
        const float2 q45 = *(const float2*)(q + 4);
        const float qa[6] = {q01.x, q01.y, q23.x, q23.y, q45.x, q45.y};

        float cq = 0.0f, sL2s2 = 0.0f, sLsc = 0.0f, sc2 = 0.0f;
#pragma unroll
        for (int i = 0; i < 6; ++i) {
            const float Li = (float)(i + 1) * 0.1f + 0.3f;  // matches reference f32 L
            cq += qa[i];
            float s, c;
            __sincosf(cq, &s, &c);
            sL2s2 += (Li * s) * (Li * s);
            sLsc  += Li * s * c;
            sc2   += c * c;
        }
        // Final combine + reciprocal in f64: protects against cancellation
        // when denom is small (cost spikes), costs ~nothing per thread.
        const double denom = 0.5 * (double)sL2s2
                           - 0.125 * (double)sLsc * (double)sLsc
                                   / (1.0 + 0.25 * (double)sc2);
        acc = 1.0 / denom;
    }

    // wave-64 butterfly reduce
#pragma unroll
    for (int off = 32; off >= 1; off >>= 1)
        acc += __shfl_down(acc, off, 64);

    const int lane = threadIdx.x & 63;
    const int wid  = threadIdx.x >> 6;
    if (lane == 0) red[wid] = acc;
    __syncthreads();
    if (threadIdx.x == 0) {
        double s = 0.0;
#pragma unroll
        for (int w = 0; w < BLK / 64; ++w) s += red[w];
        partial[blockIdx.x] = s;
    }
}

__global__ void cost_final_kernel(const double* __restrict__ partial,
                                  int n,
                                  float* __restrict__ out) {
    __shared__ double red[BLK / 64];
    double acc = 0.0;
    for (int i = threadIdx.x; i < n; i += BLK) acc += partial[i];
#pragma unroll
    for (int off = 32; off >= 1; off >>= 1)
        acc += __shfl_down(acc, off, 64);
    const int lane = threadIdx.x & 63;
    const int wid  = threadIdx.x >> 6;
    if (lane == 0) red[wid] = acc;
    __syncthreads();
    if (threadIdx.x == 0) {
        double s = 0.0;
#pragma unroll
        for (int w = 0; w < BLK / 64; ++w) s += red[w];
        out[0] = (float)s;
    }
}

extern "C" void kernel_launch(void* const* d_in, const int* in_sizes, int n_in,
                              void* d_out, int out_size, void* d_ws, size_t ws_size,
                              hipStream_t stream) {
    const float* x = (const float*)d_in[0];
    // d_in[1] = cond (unused), d_in[2] = time (gives B)
    const int B = in_sizes[2];
    const int ntasks = B * TASKS_PER_B;

    int nblocks = (ntasks + BLK - 1) / BLK;   // 416 for B=4096 (exact)
    const int max_blocks_ws = (int)(ws_size / sizeof(double));
    if (nblocks > max_blocks_ws) nblocks = max_blocks_ws > 0 ? max_blocks_ws : 1;

    double* partial = (double*)d_ws;
    float* out = (float*)d_out;

    cost_partial_kernel<<<nblocks, BLK, 0, stream>>>(x, partial, ntasks);
    cost_final_kernel<<<1, BLK, 0, stream>>>(partial, nblocks, out);
}